// Round 1
// baseline (385.699 us; speedup 1.0000x reference)
//
#include <hip/hip_runtime.h>

typedef unsigned short ushort_t;
typedef __attribute__((ext_vector_type(8))) short shortx8;
typedef __attribute__((ext_vector_type(4))) float floatx4;

#define NS 0.1f

__device__ __forceinline__ ushort_t f2bf(float f) {
  union { float f; unsigned int u; } v; v.f = f;
  unsigned int r = v.u + 0x7FFFu + ((v.u >> 16) & 1u);
  return (ushort_t)(r >> 16);
}
__device__ __forceinline__ float lk(float x) { return fmaxf(x, NS * x); }

// ---------------- weight prep: bf16 transpose to [n][k] layouts ----------------
__global__ void prep_w(const float* __restrict__ W_e1, const float* __restrict__ W_e2,
                       const float* __restrict__ W_h1, const float* __restrict__ W_h2,
                       ushort_t* __restrict__ wij, ushort_t* __restrict__ we2,
                       ushort_t* __restrict__ wh1, ushort_t* __restrict__ wh2) {
  int idx = blockIdx.x * 256 + threadIdx.x;
  if (idx < 32768) {            // wij: 256 n x 128 k
    int n = idx >> 7, k = idx & 127;
    float v = (n < 128) ? W_e1[k * 128 + n] : W_e1[(128 + k) * 128 + (n - 128)];
    wij[idx] = f2bf(v);
    return;
  }
  idx -= 32768;
  if (idx < 16384) {            // we2: 128 n x 128 k
    int n = idx >> 7, k = idx & 127;
    we2[idx] = f2bf(W_e2[k * 128 + n]);
    return;
  }
  idx -= 16384;
  if (idx < 32768) {            // wh1: 128 n x 256 k
    int n = idx >> 8, k = idx & 255;
    wh1[idx] = f2bf(W_h1[k * 128 + n]);
    return;
  }
  idx -= 32768;
  if (idx < 16384) {            // wh2: 128 n x 128 k
    int n = idx >> 7, k = idx & 127;
    wh2[idx] = f2bf(W_h2[k * 128 + n]);
  }
}

// ---------------- h0 = leaky(fres @ W_emb), K=20 ----------------
__global__ void h0_kernel(const float* __restrict__ fres, const float* __restrict__ Wemb,
                          float* __restrict__ hout) {
  int idx = blockIdx.x * 256 + threadIdx.x;   // 2048*128 total
  int row = idx >> 7, n = idx & 127;
  float a = 0.f;
#pragma unroll
  for (int k = 0; k < 20; ++k) a += fres[row * 20 + k] * Wemb[k * 128 + n];
  hout[idx] = lk(a);
}

// ---------------- generic small GEMM: C = act(A@Bt^T + bias) (+resid) ----------------
// A: M x K f32 (row stride K), Bt: N x K bf16, C: row stride ldc
__launch_bounds__(256, 2)
__global__ void gemm_bias_act(const float* __restrict__ A, const ushort_t* __restrict__ Bt,
                              const int K, const float* __restrict__ bias,
                              const float* __restrict__ resid, float* __restrict__ C,
                              const int ldc, const int act) {
  const int m0 = blockIdx.x * 64, n0 = blockIdx.y * 64;
  const int tid = threadIdx.x;
  const int w = tid >> 6, lane = tid & 63, l16 = lane & 15, lg = lane >> 4;
  __shared__ __align__(16) ushort_t sA[64][264];   // pad 8 -> row stride 528B (bank +4)

  { // stage A tile 64 x K as bf16
    const int row = tid >> 2, q = tid & 3, kq = K >> 2;
    const float* src = A + (size_t)(m0 + row) * K + q * kq;
    ushort_t* dst = &sA[row][q * kq];
    for (int x = 0; x < kq; x += 4) {
      float4 v = *(const float4*)(src + x);
      dst[x + 0] = f2bf(v.x); dst[x + 1] = f2bf(v.y);
      dst[x + 2] = f2bf(v.z); dst[x + 3] = f2bf(v.w);
    }
  }
  __syncthreads();

  floatx4 acc[4];
#pragma unroll
  for (int t = 0; t < 4; ++t) {
    float bv = bias ? bias[n0 + t * 16 + l16] : 0.f;
    acc[t] = (floatx4){bv, bv, bv, bv};
  }
  const int S = K >> 5;
  for (int s = 0; s < S; ++s) {
    shortx8 af = *(const shortx8*)&sA[w * 16 + l16][s * 32 + lg * 8];
#pragma unroll
    for (int t = 0; t < 4; ++t) {
      shortx8 bf = *(const shortx8*)(Bt + (size_t)(n0 + t * 16 + l16) * K + s * 32 + lg * 8);
      acc[t] = __builtin_amdgcn_mfma_f32_16x16x32_bf16(af, bf, acc[t], 0, 0, 0);
    }
  }
#pragma unroll
  for (int t = 0; t < 4; ++t) {
    const int n = n0 + t * 16 + l16;
#pragma unroll
    for (int r = 0; r < 4; ++r) {
      const int m = m0 + w * 16 + lg * 4 + r;
      float v = acc[t][r];
      if (act) v = lk(v);
      if (resid) v += resid[(size_t)m * ldc + n];
      C[(size_t)m * ldc + n] = v;
    }
  }
}

// ---------------- edge kernel: one block per (b,i) ----------------
// computes m = leaky(leaky(pre)@We2 + b_e2), e = sigmoid(m@W_inf+b_inf)*mask,
// m_pre = sum_j m*e  -> hm[:,128:256]; also copies h row -> hm[:,0:128]
__launch_bounds__(256, 2)
__global__ void edge_kernel(const float* __restrict__ titj, const float* __restrict__ coords,
                            const ushort_t* __restrict__ We2t, const float* __restrict__ W_e1,
                            const float* __restrict__ b_e1, const float* __restrict__ b_e2,
                            const float* __restrict__ W_inf, const float* __restrict__ b_inf,
                            const float* __restrict__ h, float* __restrict__ hm) {
  const int blk = blockIdx.x;            // b*256 + i
  const int b = blk >> 8, i = blk & 255;
  const int tid = threadIdx.x;
  const int w = tid >> 6, lane = tid & 63, l16 = lane & 15, lg = lane >> 4;

  __shared__ __align__(16) float sTiP[128];
  __shared__ __align__(16) float sWd[128];
  __shared__ __align__(16) float sD2[256];
  __shared__ __align__(16) float sMp[4][128];

  if (tid < 128) {
    sTiP[tid] = titj[(size_t)blk * 256 + tid] + b_e1[tid];
    sWd[tid] = W_e1[256 * 128 + tid];
    hm[(size_t)blk * 256 + tid] = h[(size_t)blk * 128 + tid];   // left half of hm
  }
  {
    const int j = tid;
    float dx = coords[(size_t)(b * 256 + i) * 3 + 0] - coords[(size_t)(b * 256 + j) * 3 + 0];
    float dy = coords[(size_t)(b * 256 + i) * 3 + 1] - coords[(size_t)(b * 256 + j) * 3 + 1];
    float dz = coords[(size_t)(b * 256 + i) * 3 + 2] - coords[(size_t)(b * 256 + j) * 3 + 2];
    sD2[j] = dx * dx + dy * dy + dz * dz;
  }

  // hoist the ENTIRE We2 (128x128 bf16) into this wave's registers: 32 frags = 128 VGPR
  shortx8 bfrag[4][8];
#pragma unroll
  for (int s = 0; s < 4; ++s)
#pragma unroll
    for (int t = 0; t < 8; ++t)
      bfrag[s][t] = *(const shortx8*)(We2t + (size_t)(t * 16 + l16) * 128 + s * 32 + lg * 8);

  float winfv[8], bev[8], mp[8];
#pragma unroll
  for (int t = 0; t < 8; ++t) {
    const int n = t * 16 + l16;
    winfv[t] = W_inf[n];
    bev[t] = b_e2[n];
    mp[t] = 0.f;
  }
  const float binf = b_inf[0];

  __syncthreads();

  for (int c = 0; c < 4; ++c) {
    const int jrow = c * 64 + w * 16 + l16;     // this lane's A-row (fragment layout)
    const float d2j = sD2[jrow];
    floatx4 acc[8];
#pragma unroll
    for (int t = 0; t < 8; ++t) acc[t] = (floatx4){bev[t], bev[t], bev[t], bev[t]};

#pragma unroll
    for (int s = 0; s < 4; ++s) {
      const int k0 = s * 32 + lg * 8;
      const float4* tj = (const float4*)(titj + (size_t)(b * 256 + jrow) * 256 + 128 + k0);
      float4 t0 = tj[0], t1 = tj[1];
      float4 p0 = *(const float4*)&sTiP[k0], p1 = *(const float4*)&sTiP[k0 + 4];
      float4 w0 = *(const float4*)&sWd[k0], w1 = *(const float4*)&sWd[k0 + 4];
      float pr[8];
      pr[0] = t0.x + p0.x + d2j * w0.x; pr[1] = t0.y + p0.y + d2j * w0.y;
      pr[2] = t0.z + p0.z + d2j * w0.z; pr[3] = t0.w + p0.w + d2j * w0.w;
      pr[4] = t1.x + p1.x + d2j * w1.x; pr[5] = t1.y + p1.y + d2j * w1.y;
      pr[6] = t1.z + p1.z + d2j * w1.z; pr[7] = t1.w + p1.w + d2j * w1.w;
      shortx8 af;
#pragma unroll
      for (int e = 0; e < 8; ++e) af[e] = (short)f2bf(lk(pr[e]));
#pragma unroll
      for (int t = 0; t < 8; ++t)
        acc[t] = __builtin_amdgcn_mfma_f32_16x16x32_bf16(af, bfrag[s][t], acc[t], 0, 0, 0);
    }

    // m = leaky(acc) in place; C-layout: row = lg*4+r, col n = t*16+l16
#pragma unroll
    for (int t = 0; t < 8; ++t)
#pragma unroll
      for (int r = 0; r < 4; ++r) acc[t][r] = lk(acc[t][r]);

    // logits: reduce over n (this lane covers 8 of 128 cols; rest via shfl within 16-group)
    float p[4];
#pragma unroll
    for (int r = 0; r < 4; ++r) {
      float s = 0.f;
#pragma unroll
      for (int t = 0; t < 8; ++t) s += acc[t][r] * winfv[t];
      p[r] = s;
    }
#pragma unroll
    for (int off = 1; off <= 8; off <<= 1)
#pragma unroll
      for (int r = 0; r < 4; ++r) p[r] += __shfl_xor(p[r], off);

#pragma unroll
    for (int r = 0; r < 4; ++r) {
      const int jg = c * 64 + w * 16 + lg * 4 + r;
      float x = p[r] + binf;
      float e = 1.f / (1.f + __expf(-x));
      if (jg == i) e = 0.f;
#pragma unroll
      for (int t = 0; t < 8; ++t) mp[t] += acc[t][r] * e;
    }
  }

  // reduce mp across the 4 row-groups of the wave
#pragma unroll
  for (int t = 0; t < 8; ++t) {
    mp[t] += __shfl_xor(mp[t], 16);
    mp[t] += __shfl_xor(mp[t], 32);
  }
  if (lg == 0) {
#pragma unroll
    for (int t = 0; t < 8; ++t) sMp[w][t * 16 + l16] = mp[t];
  }
  __syncthreads();
  if (tid < 128) {
    float v = sMp[0][tid] + sMp[1][tid] + sMp[2][tid] + sMp[3][tid];
    hm[(size_t)blk * 256 + 128 + tid] = v;   // right half of hm
  }
}

extern "C" void kernel_launch(void* const* d_in, const int* in_sizes, int n_in,
                              void* d_out, int out_size, void* d_ws, size_t ws_size,
                              hipStream_t stream) {
  const float* fres   = (const float*)d_in[0];
  const float* coords = (const float*)d_in[1];
  const float* W_emb  = (const float*)d_in[2];
  const float* W_e1   = (const float*)d_in[3];
  const float* b_e1   = (const float*)d_in[4];
  const float* W_e2   = (const float*)d_in[5];
  const float* b_e2   = (const float*)d_in[6];
  const float* W_inf  = (const float*)d_in[7];
  const float* b_inf  = (const float*)d_in[8];
  const float* W_h1   = (const float*)d_in[9];
  const float* b_h1   = (const float*)d_in[10];
  const float* W_h2   = (const float*)d_in[11];
  const float* b_h2   = (const float*)d_in[12];
  float* out = (float*)d_out;

  char* ws = (char*)d_ws;
  float* hA   = (float*)(ws + (0 << 20));
  float* hB   = (float*)(ws + (1 << 20));
  float* titj = (float*)(ws + (2 << 20));
  float* hm   = (float*)(ws + (4 << 20));
  float* u    = (float*)(ws + (6 << 20));
  ushort_t* wij = (ushort_t*)(ws + (7 << 20));
  ushort_t* we2 = wij + 256 * 128;
  ushort_t* wh1 = we2 + 128 * 128;
  ushort_t* wh2 = wh1 + 128 * 256;

  prep_w<<<384, 256, 0, stream>>>(W_e1, W_e2, W_h1, W_h2, wij, we2, wh1, wh2);
  h0_kernel<<<1024, 256, 0, stream>>>(fres, W_emb, hA);

  for (int it = 0; it < 2; ++it) {
    const float* hc = (it == 0) ? hA : hB;
    float* hn = (it == 0) ? hB : out;
    // [ti|tj] = h @ [W_i|W_j]  (M=2048, N=256, K=128)
    gemm_bias_act<<<dim3(32, 4), 256, 0, stream>>>(hc, wij, 128, nullptr, nullptr, titj, 256, 0);
    // edge MLP + gated reduction -> hm[:,128:], h copy -> hm[:,:128]
    edge_kernel<<<2048, 256, 0, stream>>>(titj, coords, we2, W_e1, b_e1, b_e2, W_inf, b_inf, hc, hm);
    // u = leaky(hm @ W_h1 + b_h1)   (M=2048, N=128, K=256)
    gemm_bias_act<<<dim3(32, 2), 256, 0, stream>>>(hm, wh1, 256, b_h1, nullptr, u, 128, 1);
    // h' = u @ W_h2 + b_h2 + h      (M=2048, N=128, K=128)
    gemm_bias_act<<<dim3(32, 2), 256, 0, stream>>>(u, wh2, 128, b_h2, hc, hn, 128, 0);
  }
}

// Round 2
// 235.397 us; speedup vs baseline: 1.6385x; 1.6385x over previous
//
#include <hip/hip_runtime.h>

typedef unsigned short ushort_t;
typedef __attribute__((ext_vector_type(8))) short shortx8;
typedef __attribute__((ext_vector_type(4))) float floatx4;
typedef __attribute__((ext_vector_type(2))) float floatx2;

#define NS 0.1f

__device__ __forceinline__ ushort_t f2bf(float f) {
  union { float f; unsigned int u; } v; v.f = f;
  unsigned int r = v.u + 0x7FFFu + ((v.u >> 16) & 1u);
  return (ushort_t)(r >> 16);
}
__device__ __forceinline__ float lk(float x) { return fmaxf(x, NS * x); }

// ---------------- weight prep: bf16 transpose to [n][k] layouts ----------------
__global__ void prep_w(const float* __restrict__ W_e1, const float* __restrict__ W_e2,
                       const float* __restrict__ W_h1, const float* __restrict__ W_h2,
                       ushort_t* __restrict__ wij, ushort_t* __restrict__ we2,
                       ushort_t* __restrict__ wh1, ushort_t* __restrict__ wh2) {
  int idx = blockIdx.x * 256 + threadIdx.x;
  if (idx < 32768) {            // wij: 256 n x 128 k
    int n = idx >> 7, k = idx & 127;
    float v = (n < 128) ? W_e1[k * 128 + n] : W_e1[(128 + k) * 128 + (n - 128)];
    wij[idx] = f2bf(v);
    return;
  }
  idx -= 32768;
  if (idx < 16384) {            // we2: 128 n x 128 k
    int n = idx >> 7, k = idx & 127;
    we2[idx] = f2bf(W_e2[k * 128 + n]);
    return;
  }
  idx -= 16384;
  if (idx < 32768) {            // wh1: 128 n x 256 k
    int n = idx >> 8, k = idx & 255;
    wh1[idx] = f2bf(W_h1[k * 128 + n]);
    return;
  }
  idx -= 32768;
  if (idx < 16384) {            // wh2: 128 n x 128 k
    int n = idx >> 7, k = idx & 127;
    wh2[idx] = f2bf(W_h2[k * 128 + n]);
  }
}

// ---------------- h0 = leaky(fres @ W_emb), K=20 ----------------
__global__ void h0_kernel(const float* __restrict__ fres, const float* __restrict__ Wemb,
                          float* __restrict__ hout) {
  int idx = blockIdx.x * 256 + threadIdx.x;   // 2048*128 total
  int row = idx >> 7, n = idx & 127;
  float a = 0.f;
#pragma unroll
  for (int k = 0; k < 20; ++k) a += fres[row * 20 + k] * Wemb[k * 128 + n];
  hout[idx] = lk(a);
}

// ---------------- generic small GEMM: C = act(A@Bt^T + bias) (+resid) ----------------
// A: M x K f32 (row stride K), Bt: N x K bf16, C: row stride ldc
__launch_bounds__(256, 2)
__global__ void gemm_bias_act(const float* __restrict__ A, const ushort_t* __restrict__ Bt,
                              const int K, const float* __restrict__ bias,
                              const float* __restrict__ resid, float* __restrict__ C,
                              const int ldc, const int act) {
  const int m0 = blockIdx.x * 64, n0 = blockIdx.y * 64;
  const int tid = threadIdx.x;
  const int w = tid >> 6, lane = tid & 63, l16 = lane & 15, lg = lane >> 4;
  __shared__ __align__(16) ushort_t sA[64][264];   // pad 8 -> row stride 528B

  { // stage A tile 64 x K as bf16
    const int row = tid >> 2, q = tid & 3, kq = K >> 2;
    const float* src = A + (size_t)(m0 + row) * K + q * kq;
    ushort_t* dst = &sA[row][q * kq];
    for (int x = 0; x < kq; x += 4) {
      float4 v = *(const float4*)(src + x);
      dst[x + 0] = f2bf(v.x); dst[x + 1] = f2bf(v.y);
      dst[x + 2] = f2bf(v.z); dst[x + 3] = f2bf(v.w);
    }
  }
  __syncthreads();

  floatx4 acc[4];
#pragma unroll
  for (int t = 0; t < 4; ++t) {
    float bv = bias ? bias[n0 + t * 16 + l16] : 0.f;
    acc[t] = (floatx4){bv, bv, bv, bv};
  }
  const int S = K >> 5;
  for (int s = 0; s < S; ++s) {
    shortx8 af = *(const shortx8*)&sA[w * 16 + l16][s * 32 + lg * 8];
#pragma unroll
    for (int t = 0; t < 4; ++t) {
      shortx8 bf = *(const shortx8*)(Bt + (size_t)(n0 + t * 16 + l16) * K + s * 32 + lg * 8);
      acc[t] = __builtin_amdgcn_mfma_f32_16x16x32_bf16(af, bf, acc[t], 0, 0, 0);
    }
  }
#pragma unroll
  for (int t = 0; t < 4; ++t) {
    const int n = n0 + t * 16 + l16;
#pragma unroll
    for (int r = 0; r < 4; ++r) {
      const int m = m0 + w * 16 + lg * 4 + r;
      float v = acc[t][r];
      if (act) v = lk(v);
      if (resid) v += resid[(size_t)m * ldc + n];
      C[(size_t)m * ldc + n] = v;
    }
  }
}

// ---------------- edge kernel v2: one block per (b,i), s-outer, no spills ----------------
// m = leaky(leaky(pre)@We2 + b_e2), e = sigmoid(m@W_inf+b_inf)*mask,
// m_pre = sum_j m*e  -> hm[:,128:256]; also copies h row -> hm[:,0:128]
__launch_bounds__(256, 2)
__global__ void edge_kernel(const float* __restrict__ titj, const float* __restrict__ coords,
                            const ushort_t* __restrict__ We2t, const float* __restrict__ W_e1,
                            const float* __restrict__ b_e1, const float* __restrict__ b_e2,
                            const float* __restrict__ W_inf, const float* __restrict__ b_inf,
                            const float* __restrict__ h, float* __restrict__ hm) {
  const int blk = blockIdx.x;            // b*256 + i
  const int b = blk >> 8, i = blk & 255;
  const int tid = threadIdx.x;
  const int w = tid >> 6, lane = tid & 63, l16 = lane & 15, lg = lane >> 4;

  __shared__ __align__(16) ushort_t sW[2048 * 8];   // 32 KB: We2 in fragment-linear order
  __shared__ __align__(16) float sTiP[128];
  __shared__ __align__(16) float sWd[128];
  __shared__ __align__(16) float sD2[256];
  __shared__ __align__(16) float sMp[4][128];

  if (tid < 128) {
    sTiP[tid] = titj[(size_t)blk * 256 + tid] + b_e1[tid];
    sWd[tid] = W_e1[256 * 128 + tid];
    hm[(size_t)blk * 256 + tid] = h[(size_t)blk * 128 + tid];   // left half of hm
  }
  {
    const int j = tid;
    float dx = coords[(size_t)(b * 256 + i) * 3 + 0] - coords[(size_t)(b * 256 + j) * 3 + 0];
    float dy = coords[(size_t)(b * 256 + i) * 3 + 1] - coords[(size_t)(b * 256 + j) * 3 + 1];
    float dz = coords[(size_t)(b * 256 + i) * 3 + 2] - coords[(size_t)(b * 256 + j) * 3 + 2];
    sD2[j] = dx * dx + dy * dy + dz * dz;
  }
  { // stage We2 into LDS, fragment-linear: frag f=(s*8+t)*64+ln holds B[n=t*16+(ln&15)][k=s*32+(ln>>4)*8 ..+8]
    shortx8* dst = (shortx8*)sW;
#pragma unroll
    for (int r = 0; r < 8; ++r) {
      int f = r * 256 + tid;                 // lane-consecutive LDS writes: conflict-free
      int ln = f & 63, t = (f >> 6) & 7, s = f >> 9;
      int n = t * 16 + (ln & 15), k = s * 32 + (ln >> 4) * 8;
      dst[f] = *(const shortx8*)(We2t + (size_t)n * 128 + k);
    }
  }

  float bev[8];
#pragma unroll
  for (int t = 0; t < 8; ++t) bev[t] = b_e2[t * 16 + l16];

  // acc[c][t]: rows c*64 + w*16 + (lg*4+r), cols t*16+l16  (C-layout)
  floatx4 acc[4][8];
#pragma unroll
  for (int c = 0; c < 4; ++c)
#pragma unroll
    for (int t = 0; t < 8; ++t) acc[c][t] = (floatx4){bev[t], bev[t], bev[t], bev[t]};

  __syncthreads();

  float d2j[4];
#pragma unroll
  for (int c = 0; c < 4; ++c) d2j[c] = sD2[c * 64 + w * 16 + l16];

  const shortx8* sWf = (const shortx8*)sW;
  for (int s = 0; s < 4; ++s) {
    const int k0 = s * 32 + lg * 8;          // this lane's K-slice
    shortx8 bf[8];
#pragma unroll
    for (int t = 0; t < 8; ++t) bf[t] = sWf[(s * 8 + t) * 64 + lane];
    floatx2 p2[4], w2[4];
#pragma unroll
    for (int x = 0; x < 4; ++x) {
      p2[x] = *(const floatx2*)&sTiP[k0 + 2 * x];
      w2[x] = *(const floatx2*)&sWd[k0 + 2 * x];
    }
#pragma unroll
    for (int c = 0; c < 4; ++c) {
      const int jrow = c * 64 + w * 16 + l16;
      const floatx2* tj2 = (const floatx2*)(titj + (size_t)(b * 256 + jrow) * 256 + 128 + k0);
      const floatx2 d2v = (floatx2){d2j[c], d2j[c]};
      const floatx2 nsv = (floatx2){NS, NS};
      shortx8 af;
#pragma unroll
      for (int x = 0; x < 4; ++x) {
        floatx2 pr = tj2[x] + p2[x] + d2v * w2[x];     // v_pk_add/fma
        floatx2 lkv = __builtin_elementwise_max(pr, pr * nsv);
        af[2 * x + 0] = (short)f2bf(lkv.x);
        af[2 * x + 1] = (short)f2bf(lkv.y);
      }
#pragma unroll
      for (int t = 0; t < 8; ++t)
        acc[c][t] = __builtin_amdgcn_mfma_f32_16x16x32_bf16(af, bf[t], acc[c][t], 0, 0, 0);
    }
  }

  // epilogue: leaky, gate, masked weighted reduction
  float winfv[8], mp[8];
#pragma unroll
  for (int t = 0; t < 8; ++t) { winfv[t] = W_inf[t * 16 + l16]; mp[t] = 0.f; }
  const float binf = b_inf[0];

#pragma unroll
  for (int c = 0; c < 4; ++c) {
#pragma unroll
    for (int t = 0; t < 8; ++t)
#pragma unroll
      for (int r = 0; r < 4; ++r) acc[c][t][r] = lk(acc[c][t][r]);

    float p[4];
#pragma unroll
    for (int r = 0; r < 4; ++r) {
      float s = 0.f;
#pragma unroll
      for (int t = 0; t < 8; ++t) s += acc[c][t][r] * winfv[t];
      p[r] = s;
    }
#pragma unroll
    for (int off = 1; off <= 8; off <<= 1)
#pragma unroll
      for (int r = 0; r < 4; ++r) p[r] += __shfl_xor(p[r], off);

#pragma unroll
    for (int r = 0; r < 4; ++r) {
      const int jg = c * 64 + w * 16 + lg * 4 + r;
      float x = p[r] + binf;
      float e = 1.f / (1.f + __expf(-x));
      if (jg == i) e = 0.f;
#pragma unroll
      for (int t = 0; t < 8; ++t) mp[t] += acc[c][t][r] * e;
    }
  }

  // reduce mp across the 4 row-groups of the wave, then across waves
#pragma unroll
  for (int t = 0; t < 8; ++t) {
    mp[t] += __shfl_xor(mp[t], 16);
    mp[t] += __shfl_xor(mp[t], 32);
  }
  if (lg == 0) {
#pragma unroll
    for (int t = 0; t < 8; ++t) sMp[w][t * 16 + l16] = mp[t];
  }
  __syncthreads();
  if (tid < 128) {
    float v = sMp[0][tid] + sMp[1][tid] + sMp[2][tid] + sMp[3][tid];
    hm[(size_t)blk * 256 + 128 + tid] = v;   // right half of hm
  }
}

extern "C" void kernel_launch(void* const* d_in, const int* in_sizes, int n_in,
                              void* d_out, int out_size, void* d_ws, size_t ws_size,
                              hipStream_t stream) {
  const float* fres   = (const float*)d_in[0];
  const float* coords = (const float*)d_in[1];
  const float* W_emb  = (const float*)d_in[2];
  const float* W_e1   = (const float*)d_in[3];
  const float* b_e1   = (const float*)d_in[4];
  const float* W_e2   = (const float*)d_in[5];
  const float* b_e2   = (const float*)d_in[6];
  const float* W_inf  = (const float*)d_in[7];
  const float* b_inf  = (const float*)d_in[8];
  const float* W_h1   = (const float*)d_in[9];
  const float* b_h1   = (const float*)d_in[10];
  const float* W_h2   = (const float*)d_in[11];
  const float* b_h2   = (const float*)d_in[12];
  float* out = (float*)d_out;

  char* ws = (char*)d_ws;
  float* hA   = (float*)(ws + (0 << 20));
  float* hB   = (float*)(ws + (1 << 20));
  float* titj = (float*)(ws + (2 << 20));
  float* hm   = (float*)(ws + (4 << 20));
  float* u    = (float*)(ws + (6 << 20));
  ushort_t* wij = (ushort_t*)(ws + (7 << 20));
  ushort_t* we2 = wij + 256 * 128;
  ushort_t* wh1 = we2 + 128 * 128;
  ushort_t* wh2 = wh1 + 128 * 256;

  prep_w<<<384, 256, 0, stream>>>(W_e1, W_e2, W_h1, W_h2, wij, we2, wh1, wh2);
  h0_kernel<<<1024, 256, 0, stream>>>(fres, W_emb, hA);

  for (int it = 0; it < 2; ++it) {
    const float* hc = (it == 0) ? hA : hB;
    float* hn = (it == 0) ? hB : out;
    // [ti|tj] = h @ [W_i|W_j]  (M=2048, N=256, K=128)
    gemm_bias_act<<<dim3(32, 4), 256, 0, stream>>>(hc, wij, 128, nullptr, nullptr, titj, 256, 0);
    // edge MLP + gated reduction -> hm[:,128:], h copy -> hm[:,:128]
    edge_kernel<<<2048, 256, 0, stream>>>(titj, coords, we2, W_e1, b_e1, b_e2, W_inf, b_inf, hc, hm);
    // u = leaky(hm @ W_h1 + b_h1)   (M=2048, N=128, K=256)
    gemm_bias_act<<<dim3(32, 2), 256, 0, stream>>>(hm, wh1, 256, b_h1, nullptr, u, 128, 1);
    // h' = u @ W_h2 + b_h2 + h      (M=2048, N=128, K=128)
    gemm_bias_act<<<dim3(32, 2), 256, 0, stream>>>(u, wh2, 128, b_h2, hc, hn, 128, 0);
  }
}

// Round 3
// 180.227 us; speedup vs baseline: 2.1401x; 1.3061x over previous
//
#include <hip/hip_runtime.h>

typedef unsigned short ushort_t;
typedef __attribute__((ext_vector_type(8))) short shortx8;
typedef __attribute__((ext_vector_type(4))) float floatx4;
typedef __attribute__((ext_vector_type(2))) float floatx2;

#define NS 0.1f

__device__ __forceinline__ ushort_t f2bf_rne(float f) {
  union { float f; unsigned int u; } v; v.f = f;
  unsigned int r = v.u + 0x7FFFu + ((v.u >> 16) & 1u);
  return (ushort_t)(r >> 16);
}
// pack two f32 -> bf16x2 (round-half-up) in one v_perm: low16=bf(a), high16=bf(b)
__device__ __forceinline__ unsigned int pk2bf(float a, float b) {
  union { float f; unsigned int u; } x, y; x.f = a; y.f = b;
  return __builtin_amdgcn_perm(y.u + 0x8000u, x.u + 0x8000u, 0x07060302u);
}
__device__ __forceinline__ ushort_t f2bf_rhu(float f) {
  union { float f; unsigned int u; } v; v.f = f;
  return (ushort_t)((v.u + 0x8000u) >> 16);
}
__device__ __forceinline__ float lk(float x) { return fmaxf(x, NS * x); }
__device__ __forceinline__ floatx2 lk2(floatx2 v) {
  return __builtin_elementwise_max(v, v * (floatx2){NS, NS});
}

// fragment-linear weight layout: element e = f*8+j, f = (s*NT + t)*64 + lane,
// value = W[k = s*32 + (lane>>4)*8 + j][n = t*16 + (lane&15)]  (W is KxN row-major)
__global__ __launch_bounds__(256) void prep_w(
    const float* __restrict__ W_e1, const float* __restrict__ W_e2,
    const float* __restrict__ W_h1, const float* __restrict__ W_h2,
    ushort_t* __restrict__ wijf, ushort_t* __restrict__ we2f,
    ushort_t* __restrict__ wh1f, ushort_t* __restrict__ wh2f) {
  int e = blockIdx.x * 256 + threadIdx.x;
  int which, le;
  if (e < 32768) { which = 0; le = e; }
  else if (e < 49152) { which = 1; le = e - 32768; }
  else if (e < 81920) { which = 2; le = e - 49152; }
  else { which = 3; le = e - 81920; }
  const int NT = (which == 0) ? 16 : 8;
  int f = le >> 3, j = le & 7;
  int lane = f & 63, ft = f >> 6;
  int t = ft % NT, s = ft / NT;
  int n = t * 16 + (lane & 15), k = s * 32 + (lane >> 4) * 8 + j;
  float v; ushort_t* d;
  if (which == 0) { v = (n < 128) ? W_e1[k * 128 + n] : W_e1[(128 + k) * 128 + (n - 128)]; d = wijf; }
  else if (which == 1) { v = W_e2[k * 128 + n]; d = we2f; }
  else if (which == 2) { v = W_h1[k * 128 + n]; d = wh1f; }
  else { v = W_h2[k * 128 + n]; d = wh2f; }
  d[le] = f2bf_rne(v);
}

// proj epilogue store: ti plain [m][n<128]; tj fragment-linear for the edge kernel:
// tjf[(((b*4 + s)*256 + j)*4 + lg)*8 + j8] = tj[j][k], k = s*32+lg*8+j8
__device__ __forceinline__ void proj_store(float v, int m, int n,
                                           float* __restrict__ ti, float* __restrict__ tjf) {
  if (n < 128) {
    ti[(size_t)m * 128 + n] = v;
  } else {
    int k = n - 128, b = m >> 8, j = m & 255;
    int s = k >> 5, lg2 = (k >> 3) & 3, j8 = k & 7;
    tjf[((((size_t)(b * 4 + s)) * 256 + j) * 4 + lg2) * 8 + j8] = v;
  }
}

// ---------------- h0 = leaky(fres @ W_emb) fused with proj [ti|tj] = h0 @ Wij ----------------
__global__ __launch_bounds__(256) void h0_proj(
    const float* __restrict__ fres, const float* __restrict__ Wemb,
    const ushort_t* __restrict__ wijf, float* __restrict__ h_out,
    float* __restrict__ ti, float* __restrict__ tjf) {
  const int m0 = blockIdx.x * 16;
  const int tid = threadIdx.x;
  const int w = tid >> 6, lane = tid & 63, l16 = lane & 15, lg = lane >> 4;
  __shared__ __align__(16) ushort_t sH[16][136];
  {
    const int row = tid >> 4, c0 = (tid & 15) * 8;
    const float* fr = fres + (size_t)(m0 + row) * 20;
    float a[8] = {0, 0, 0, 0, 0, 0, 0, 0};
    for (int k = 0; k < 20; ++k) {
      float fv = fr[k];
      float4 w0 = *(const float4*)(Wemb + k * 128 + c0);
      float4 w1 = *(const float4*)(Wemb + k * 128 + c0 + 4);
      a[0] += fv * w0.x; a[1] += fv * w0.y; a[2] += fv * w0.z; a[3] += fv * w0.w;
      a[4] += fv * w1.x; a[5] += fv * w1.y; a[6] += fv * w1.z; a[7] += fv * w1.w;
    }
#pragma unroll
    for (int x = 0; x < 8; ++x) a[x] = lk(a[x]);
    float* ho = h_out + (size_t)(m0 + row) * 128 + c0;
    *(float4*)ho = (float4){a[0], a[1], a[2], a[3]};
    *(float4*)(ho + 4) = (float4){a[4], a[5], a[6], a[7]};
    unsigned int* sh = (unsigned int*)&sH[row][c0];
    sh[0] = pk2bf(a[0], a[1]); sh[1] = pk2bf(a[2], a[3]);
    sh[2] = pk2bf(a[4], a[5]); sh[3] = pk2bf(a[6], a[7]);
  }
  __syncthreads();
  floatx4 ap[4];
#pragma unroll
  for (int q = 0; q < 4; ++q) ap[q] = (floatx4){0.f, 0.f, 0.f, 0.f};
  const shortx8* Wp = (const shortx8*)wijf;
#pragma unroll
  for (int s = 0; s < 4; ++s) {
    shortx8 af = *(const shortx8*)&sH[l16][s * 32 + lg * 8];
#pragma unroll
    for (int q = 0; q < 4; ++q)
      ap[q] = __builtin_amdgcn_mfma_f32_16x16x32_bf16(af, Wp[(s * 16 + 4 * w + q) * 64 + lane], ap[q], 0, 0, 0);
  }
#pragma unroll
  for (int q = 0; q < 4; ++q) {
    const int n = (4 * w + q) * 16 + l16;
#pragma unroll
    for (int r = 0; r < 4; ++r) proj_store(ap[q][r], m0 + lg * 4 + r, n, ti, tjf);
  }
}

// ---------------- edge kernel v3: 2 blocks per (b,i), 32 rows/wave ----------------
__global__ __launch_bounds__(256, 3) void edge_kernel(
    const float* __restrict__ ti, const float* __restrict__ tjf,
    const float* __restrict__ coords, const ushort_t* __restrict__ we2f,
    const float* __restrict__ W_e1, const float* __restrict__ b_e1,
    const float* __restrict__ b_e2, const float* __restrict__ W_inf,
    const float* __restrict__ b_inf, float* __restrict__ mp0, float* __restrict__ mp1) {
  const int blk = blockIdx.x;
  const int b = blk >> 9, i = (blk >> 1) & 255, ch = blk & 1;
  const int tid = threadIdx.x;
  const int w = tid >> 6, lane = tid & 63, l16 = lane & 15, lg = lane >> 4;

  __shared__ __align__(16) ushort_t sW[16384];   // 32 KB We2 fragment-linear
  __shared__ __align__(16) float sTiP[128];
  __shared__ __align__(16) float sWd[128];
  __shared__ __align__(16) float sD2[128];
  __shared__ __align__(16) float sMp[4][128];

  {
    shortx8* dst = (shortx8*)sW;
    const shortx8* src = (const shortx8*)we2f;
#pragma unroll
    for (int r = 0; r < 8; ++r) dst[r * 256 + tid] = src[r * 256 + tid];
  }
  if (tid < 128) {
    sTiP[tid] = ti[(size_t)(b * 256 + i) * 128 + tid] + b_e1[tid];
    sWd[tid] = W_e1[256 * 128 + tid];
    const int j = ch * 128 + tid;
    float dx = coords[(size_t)(b * 256 + i) * 3 + 0] - coords[(size_t)(b * 256 + j) * 3 + 0];
    float dy = coords[(size_t)(b * 256 + i) * 3 + 1] - coords[(size_t)(b * 256 + j) * 3 + 1];
    float dz = coords[(size_t)(b * 256 + i) * 3 + 2] - coords[(size_t)(b * 256 + j) * 3 + 2];
    sD2[tid] = dx * dx + dy * dy + dz * dz;
  }
  floatx4 acc[2][8];
#pragma unroll
  for (int t = 0; t < 8; ++t) {
    float bv = b_e2[t * 16 + l16];
    acc[0][t] = (floatx4){bv, bv, bv, bv};
    acc[1][t] = acc[0][t];
  }
  __syncthreads();

  float d2a[2];
  d2a[0] = sD2[w * 16 + l16];
  d2a[1] = sD2[64 + w * 16 + l16];
  const shortx8* sWf = (const shortx8*)sW;

#pragma unroll
  for (int s = 0; s < 4; ++s) {
    const int k0 = s * 32 + lg * 8;
    floatx2 p2[4], w2[4];
#pragma unroll
    for (int x = 0; x < 4; ++x) {
      p2[x] = *(const floatx2*)&sTiP[k0 + 2 * x];
      w2[x] = *(const floatx2*)&sWd[k0 + 2 * x];
    }
    shortx8 af[2];
#pragma unroll
    for (int c = 0; c < 2; ++c) {
      const int jr = ch * 128 + c * 64 + w * 16 + l16;   // j within batch
      const float* tb = tjf + (((size_t)(b * 4 + s) * 256 + jr) * 4 + lg) * 8;
      float4 t0 = *(const float4*)tb;
      float4 t1 = *(const float4*)(tb + 4);
      const floatx2 d2v = (floatx2){d2a[c], d2a[c]};
      floatx2 pr0 = (floatx2){t0.x, t0.y} + (p2[0] + d2v * w2[0]);
      floatx2 pr1 = (floatx2){t0.z, t0.w} + (p2[1] + d2v * w2[1]);
      floatx2 pr2 = (floatx2){t1.x, t1.y} + (p2[2] + d2v * w2[2]);
      floatx2 pr3 = (floatx2){t1.z, t1.w} + (p2[3] + d2v * w2[3]);
      floatx2 l0 = lk2(pr0), l1 = lk2(pr1), l2 = lk2(pr2), l3 = lk2(pr3);
      union { shortx8 s8; unsigned int u[4]; } A;
      A.u[0] = pk2bf(l0.x, l0.y); A.u[1] = pk2bf(l1.x, l1.y);
      A.u[2] = pk2bf(l2.x, l2.y); A.u[3] = pk2bf(l3.x, l3.y);
      af[c] = A.s8;
    }
#pragma unroll
    for (int tg = 0; tg < 2; ++tg) {
      shortx8 b0 = sWf[(s * 8 + tg * 4 + 0) * 64 + lane];
      shortx8 b1 = sWf[(s * 8 + tg * 4 + 1) * 64 + lane];
      shortx8 b2 = sWf[(s * 8 + tg * 4 + 2) * 64 + lane];
      shortx8 b3 = sWf[(s * 8 + tg * 4 + 3) * 64 + lane];
#pragma unroll
      for (int c = 0; c < 2; ++c) {
        acc[c][tg * 4 + 0] = __builtin_amdgcn_mfma_f32_16x16x32_bf16(af[c], b0, acc[c][tg * 4 + 0], 0, 0, 0);
        acc[c][tg * 4 + 1] = __builtin_amdgcn_mfma_f32_16x16x32_bf16(af[c], b1, acc[c][tg * 4 + 1], 0, 0, 0);
        acc[c][tg * 4 + 2] = __builtin_amdgcn_mfma_f32_16x16x32_bf16(af[c], b2, acc[c][tg * 4 + 2], 0, 0, 0);
        acc[c][tg * 4 + 3] = __builtin_amdgcn_mfma_f32_16x16x32_bf16(af[c], b3, acc[c][tg * 4 + 3], 0, 0, 0);
      }
    }
  }

  // epilogue: leaky, gate, masked weighted reduction
  float winfv[8], mp[8];
#pragma unroll
  for (int t = 0; t < 8; ++t) { winfv[t] = W_inf[t * 16 + l16]; mp[t] = 0.f; }
  const float binf = b_inf[0];
#pragma unroll
  for (int c = 0; c < 2; ++c) {
#pragma unroll
    for (int t = 0; t < 8; ++t) {
      floatx2 v0 = lk2((floatx2){acc[c][t][0], acc[c][t][1]});
      floatx2 v1 = lk2((floatx2){acc[c][t][2], acc[c][t][3]});
      acc[c][t][0] = v0.x; acc[c][t][1] = v0.y; acc[c][t][2] = v1.x; acc[c][t][3] = v1.y;
    }
    float p[4];
#pragma unroll
    for (int r = 0; r < 4; ++r) {
      float sum = 0.f;
#pragma unroll
      for (int t = 0; t < 8; ++t) sum += acc[c][t][r] * winfv[t];
      p[r] = sum;
    }
#pragma unroll
    for (int off = 1; off <= 8; off <<= 1)
#pragma unroll
      for (int r = 0; r < 4; ++r) p[r] += __shfl_xor(p[r], off);
#pragma unroll
    for (int r = 0; r < 4; ++r) {
      const int jg = ch * 128 + c * 64 + w * 16 + lg * 4 + r;
      float x = p[r] + binf;
      float e = __builtin_amdgcn_rcpf(1.f + __expf(-x));
      if (jg == i) e = 0.f;
#pragma unroll
      for (int t = 0; t < 8; ++t) mp[t] += acc[c][t][r] * e;
    }
  }
#pragma unroll
  for (int t = 0; t < 8; ++t) {
    mp[t] += __shfl_xor(mp[t], 16);
    mp[t] += __shfl_xor(mp[t], 32);
  }
  if (lg == 0) {
#pragma unroll
    for (int t = 0; t < 8; ++t) sMp[w][t * 16 + l16] = mp[t];
  }
  __syncthreads();
  if (tid < 128) {
    float v = sMp[0][tid] + sMp[1][tid] + sMp[2][tid] + sMp[3][tid];
    float* mpo = ch ? mp1 : mp0;
    mpo[(size_t)(b * 256 + i) * 128 + tid] = v;
  }
}

// ---------------- fused node MLP (+ next-iteration proj) ----------------
// hm = [h | mp0+mp1]; u = leaky(hm@W_h1+b_h1); h' = u@W_h2+b_h2+h; [ti|tj] = h'@Wij
__global__ __launch_bounds__(256) void node_kernel(
    const float* __restrict__ h_in, const float* __restrict__ mp0, const float* __restrict__ mp1,
    const ushort_t* __restrict__ wh1f, const float* __restrict__ b_h1,
    const ushort_t* __restrict__ wh2f, const float* __restrict__ b_h2,
    const ushort_t* __restrict__ wijf, float* __restrict__ h_out,
    float* __restrict__ ti, float* __restrict__ tjf, const int do_proj) {
  const int m0 = blockIdx.x * 16;
  const int tid = threadIdx.x;
  const int w = tid >> 6, lane = tid & 63, l16 = lane & 15, lg = lane >> 4;
  __shared__ __align__(16) ushort_t sA[16][264];
  __shared__ __align__(16) ushort_t sU[16][136];
  __shared__ __align__(16) ushort_t sHp[16][136];

  {
    const int row = tid >> 4, c0 = (tid & 15) * 16;
    unsigned int* dst = (unsigned int*)&sA[row][c0];
    if (c0 < 128) {
      const float* src = h_in + (size_t)(m0 + row) * 128 + c0;
#pragma unroll
      for (int x = 0; x < 8; ++x) dst[x] = pk2bf(src[2 * x], src[2 * x + 1]);
    } else {
      const float* s0 = mp0 + (size_t)(m0 + row) * 128 + (c0 - 128);
      const float* s1 = mp1 + (size_t)(m0 + row) * 128 + (c0 - 128);
#pragma unroll
      for (int x = 0; x < 8; ++x)
        dst[x] = pk2bf(s0[2 * x] + s1[2 * x], s0[2 * x + 1] + s1[2 * x + 1]);
    }
  }
  __syncthreads();
  // u tiles {2w, 2w+1}
  floatx4 au[2];
#pragma unroll
  for (int q = 0; q < 2; ++q) { float bv = b_h1[(2 * w + q) * 16 + l16]; au[q] = (floatx4){bv, bv, bv, bv}; }
  const shortx8* W1 = (const shortx8*)wh1f;
#pragma unroll
  for (int s = 0; s < 8; ++s) {
    shortx8 af = *(const shortx8*)&sA[l16][s * 32 + lg * 8];
#pragma unroll
    for (int q = 0; q < 2; ++q)
      au[q] = __builtin_amdgcn_mfma_f32_16x16x32_bf16(af, W1[(s * 8 + 2 * w + q) * 64 + lane], au[q], 0, 0, 0);
  }
#pragma unroll
  for (int q = 0; q < 2; ++q)
#pragma unroll
    for (int r = 0; r < 4; ++r)
      sU[lg * 4 + r][(2 * w + q) * 16 + l16] = f2bf_rhu(lk(au[q][r]));
  __syncthreads();
  // h' tiles {2w, 2w+1}
  floatx4 ah[2];
#pragma unroll
  for (int q = 0; q < 2; ++q) { float bv = b_h2[(2 * w + q) * 16 + l16]; ah[q] = (floatx4){bv, bv, bv, bv}; }
  const shortx8* W2 = (const shortx8*)wh2f;
#pragma unroll
  for (int s = 0; s < 4; ++s) {
    shortx8 af = *(const shortx8*)&sU[l16][s * 32 + lg * 8];
#pragma unroll
    for (int q = 0; q < 2; ++q)
      ah[q] = __builtin_amdgcn_mfma_f32_16x16x32_bf16(af, W2[(s * 8 + 2 * w + q) * 64 + lane], ah[q], 0, 0, 0);
  }
#pragma unroll
  for (int q = 0; q < 2; ++q) {
    const int n = (2 * w + q) * 16 + l16;
#pragma unroll
    for (int r = 0; r < 4; ++r) {
      const int m = m0 + lg * 4 + r;
      float v = ah[q][r] + h_in[(size_t)m * 128 + n];
      h_out[(size_t)m * 128 + n] = v;
      sHp[lg * 4 + r][n] = f2bf_rhu(v);
    }
  }
  if (!do_proj) return;
  __syncthreads();
  // proj tiles {4w..4w+3}
  floatx4 ap[4];
#pragma unroll
  for (int q = 0; q < 4; ++q) ap[q] = (floatx4){0.f, 0.f, 0.f, 0.f};
  const shortx8* Wp = (const shortx8*)wijf;
#pragma unroll
  for (int s = 0; s < 4; ++s) {
    shortx8 af = *(const shortx8*)&sHp[l16][s * 32 + lg * 8];
#pragma unroll
    for (int q = 0; q < 4; ++q)
      ap[q] = __builtin_amdgcn_mfma_f32_16x16x32_bf16(af, Wp[(s * 16 + 4 * w + q) * 64 + lane], ap[q], 0, 0, 0);
  }
#pragma unroll
  for (int q = 0; q < 4; ++q) {
    const int n = (4 * w + q) * 16 + l16;
#pragma unroll
    for (int r = 0; r < 4; ++r) proj_store(ap[q][r], m0 + lg * 4 + r, n, ti, tjf);
  }
}

extern "C" void kernel_launch(void* const* d_in, const int* in_sizes, int n_in,
                              void* d_out, int out_size, void* d_ws, size_t ws_size,
                              hipStream_t stream) {
  const float* fres   = (const float*)d_in[0];
  const float* coords = (const float*)d_in[1];
  const float* W_emb  = (const float*)d_in[2];
  const float* W_e1   = (const float*)d_in[3];
  const float* b_e1   = (const float*)d_in[4];
  const float* W_e2   = (const float*)d_in[5];
  const float* b_e2   = (const float*)d_in[6];
  const float* W_inf  = (const float*)d_in[7];
  const float* b_inf  = (const float*)d_in[8];
  const float* W_h1   = (const float*)d_in[9];
  const float* b_h1   = (const float*)d_in[10];
  const float* W_h2   = (const float*)d_in[11];
  const float* b_h2   = (const float*)d_in[12];
  float* out = (float*)d_out;

  char* ws = (char*)d_ws;
  float* hA  = (float*)(ws + (0 << 20));
  float* hB  = (float*)(ws + (1 << 20));
  float* tib = (float*)(ws + (2 << 20));
  float* tjf = (float*)(ws + (3 << 20));
  float* mp0 = (float*)(ws + (4 << 20));
  float* mp1 = (float*)(ws + (5 << 20));
  ushort_t* wijf = (ushort_t*)(ws + (6 << 20));
  ushort_t* we2f = wijf + 32768;
  ushort_t* wh1f = we2f + 16384;
  ushort_t* wh2f = wh1f + 32768;

  prep_w<<<384, 256, 0, stream>>>(W_e1, W_e2, W_h1, W_h2, wijf, we2f, wh1f, wh2f);
  h0_proj<<<128, 256, 0, stream>>>(fres, W_emb, wijf, hA, tib, tjf);

  edge_kernel<<<4096, 256, 0, stream>>>(tib, tjf, coords, we2f, W_e1, b_e1, b_e2, W_inf, b_inf, mp0, mp1);
  node_kernel<<<128, 256, 0, stream>>>(hA, mp0, mp1, wh1f, b_h1, wh2f, b_h2, wijf, hB, tib, tjf, 1);

  edge_kernel<<<4096, 256, 0, stream>>>(tib, tjf, coords, we2f, W_e1, b_e1, b_e2, W_inf, b_inf, mp0, mp1);
  node_kernel<<<128, 256, 0, stream>>>(hB, mp0, mp1, wh1f, b_h1, wh2f, b_h2, wijf, out, tib, tjf, 0);
}